// Round 18
// baseline (1733.822 us; speedup 1.0000x reference)
//
#include <hip/hip_runtime.h>
#include <stdint.h>
#include <stddef.h>

#define BATCH 128
#define NFRAMES 256
#define EMBED 768
#define RES 2048
#define NCLS 1000
#define NWG 256

typedef __attribute__((ext_vector_type(8))) short bf16x8;
typedef __attribute__((ext_vector_type(4))) float f32x4;
typedef unsigned short u16;

__device__ inline u16 f2bf(float f) {
    union { float f; unsigned u; } v; v.f = f;
    unsigned r = v.u + 0x7FFFu + ((v.u >> 16) & 1u);
    return (u16)(r >> 16);
}
// tanh(x) = 1 - 2/(e^{2x}+1), via HW exp2 + rcp (saturates correctly; NEVER NaN)
__device__ inline float tanh_fast(float x) {
    float z = __builtin_amdgcn_exp2f(x * 2.885390081777927f);  // e^{2x}
    return 1.f - 2.f * __builtin_amdgcn_rcpf(z + 1.f);
}

// ---------------- fp32 -> bf16 convert, vectorized x4 ----------------
__global__ __launch_bounds__(256) void cvt_kernel(const float* __restrict__ in,
                                                  u16* __restrict__ out, int n4) {
    int i = blockIdx.x * blockDim.x + threadIdx.x;
    int stride = gridDim.x * blockDim.x;
    for (; i < n4; i += stride) {
        float4 v = ((const float4*)in)[i];
        ushort4 o;
        o.x = f2bf(v.x); o.y = f2bf(v.y); o.z = f2bf(v.z); o.w = f2bf(v.w);
        ((ushort4*)out)[i] = o;
    }
}

// ---------------- persistent recurrence: fused proj + SENTINEL dataflow sync ----------------
// 8 row-groups x 32 col-blocks = 256 WGs, tile 16 rows x 64 cols, 8 waves.
// Ring slot t holds state[t]; ring pre-filled with 0xFFFF (-NaN bf16), which
// tanh can never produce. Stores are dword-atomic, so a dword is either
// 0xFFFFFFFF (unwritten) or two valid tanh outputs. Consumers POLL THEIR OWN
// A-DATA with uncached loads until sentinel-free -> the store IS the signal:
// no flags, no stamps, no store-drain, no end-of-step barrier (ring never
// reuses addresses => no WAR hazard). x-MFMAs run under the first poll trip.
__global__ __launch_bounds__(512, 1) void recur_kernel(const u16* __restrict__ res,
                                                       const u16* __restrict__ win,
                                                       const u16* __restrict__ xb,
                                                       u16* __restrict__ ring,
                                                       const u16* __restrict__ s0) {
    __shared__ float part[8][16][66];
    const int lane = threadIdx.x & 63;
    const int w = threadIdx.x >> 6;
    const int rowgrp = (int)(blockIdx.x & 7);
    const int colblk = (int)(blockIdx.x >> 3);
    const int m0 = rowgrp * 16;
    const int n0 = colblk * 64;
    const int lr = lane & 15;
    const int lk = (lane >> 4) * 8;
    const int rb = (lane >> 4) * 4;
    const int kbase = w * 256;       // state-GEMM K slice
    const int xkbase = w * 96;       // input-GEMM K slice (768/8)

    // reservoir B-fragments (4 col-frags x 8 K-subs)
    bf16x8 bfr[4][8];
#pragma unroll
    for (int jf = 0; jf < 4; jf++)
#pragma unroll
        for (int kk = 0; kk < 8; kk++)
            bfr[jf][kk] = *(const bf16x8*)(res + (size_t)(n0 + jf * 16 + lr) * RES + kbase + kk * 32 + lk);

    // W_in B-fragments (4 col-frags x 3 K-subs of 32)
    bf16x8 wfr[4][3];
#pragma unroll
    for (int jf = 0; jf < 4; jf++)
#pragma unroll
        for (int j = 0; j < 3; j++)
            wfr[jf][j] = *(const bf16x8*)(win + (size_t)(n0 + jf * 16 + lr) * EMBED + xkbase + j * 32 + lk);

    const int er = threadIdx.x >> 5;          // 0..15
    const int ec = (threadIdx.x & 31) * 2;    // 0..62
    const size_t gidx = (size_t)(m0 + er) * RES + n0 + ec;
    const u16* xrow = xb + (size_t)(m0 + lr) * NFRAMES * EMBED + xkbase + lk;

    for (int t = 0; t < NFRAMES; t++) {
        const u16* sin = (t == 0) ? s0 : ring + (size_t)(t - 1) * BATCH * RES;
        u16* sout = ring + (size_t)t * BATCH * RES;
        const u16* abase = sin + (size_t)(m0 + lr) * RES + kbase + lk;
        const u16* xp = xrow + (size_t)t * EMBED;

        // issue state A-loads (uncached: sentinel retries must reach the IF)
        bf16x8 a[8];
#pragma unroll
        for (int kk = 0; kk < 8; kk++)
            asm volatile("global_load_dwordx4 %0, %1, off sc0 sc1"
                         : "=v"(a[kk]) : "v"(abase + kk * 32));
        // x loads (cached, immutable)
        bf16x8 xa[3];
#pragma unroll
        for (int j = 0; j < 3; j++)
            asm volatile("global_load_dwordx4 %0, %1, off"
                         : "=v"(xa[j]) : "v"(xp + j * 32));

        f32x4 acc[4];
#pragma unroll
        for (int jf = 0; jf < 4; jf++) acc[jf] = (f32x4)0.f;

        // x-projection MFMAs under the A-loads' first round trip
        asm volatile("s_waitcnt vmcnt(8)" ::: "memory");  // wait a-loads? no: xa are LAST 3 issued
        __builtin_amdgcn_sched_barrier(0);
        // NOTE: xa issued after a[], so vmcnt(8) means xa NOT ready yet; wait properly:
        asm volatile("s_waitcnt vmcnt(0)" ::: "memory");
        __builtin_amdgcn_sched_barrier(0);
#pragma unroll
        for (int j = 0; j < 3; j++)
#pragma unroll
            for (int jf = 0; jf < 4; jf++)
                acc[jf] = __builtin_amdgcn_mfma_f32_16x16x32_bf16(xa[j], wfr[jf][j], acc[jf], 0, 0, 0);

        // sentinel poll on the state data (first attempt uses the loads above)
        while (1) {
            int ok = 1;
#pragma unroll
            for (int kk = 0; kk < 8; kk++) {
                const unsigned* dw = (const unsigned*)&a[kk];
#pragma unroll
                for (int d = 0; d < 4; d++) ok &= (dw[d] != 0xFFFFFFFFu);
            }
            if (__all(ok)) break;
            __builtin_amdgcn_s_sleep(1);
#pragma unroll
            for (int kk = 0; kk < 8; kk++)
                asm volatile("global_load_dwordx4 %0, %1, off sc0 sc1"
                             : "=v"(a[kk]) : "v"(abase + kk * 32));
            asm volatile("s_waitcnt vmcnt(0)" ::: "memory");
            __builtin_amdgcn_sched_barrier(0);
        }
        __builtin_amdgcn_sched_barrier(0);

        // state MFMAs
#pragma unroll
        for (int kk = 0; kk < 8; kk++)
#pragma unroll
            for (int jf = 0; jf < 4; jf++)
                acc[jf] = __builtin_amdgcn_mfma_f32_16x16x32_bf16(a[kk], bfr[jf][kk], acc[jf], 0, 0, 0);

        // K-partials -> LDS (barrier also separates step t-1's reduce reads)
#pragma unroll
        for (int jf = 0; jf < 4; jf++)
#pragma unroll
            for (int q = 0; q < 4; q++)
                part[w][rb + q][jf * 16 + lr] = acc[jf][q];
        __syncthreads();

        // reduce 8 partials + tanh + packed write-through store (the "signal")
        float sx = 0.f, sy = 0.f;
#pragma unroll
        for (int ww = 0; ww < 8; ww++) {
            float2 v = *(const float2*)&part[ww][er][ec];
            sx += v.x; sy += v.y;
        }
        float v0 = tanh_fast(sx);
        float v1 = tanh_fast(sy);
        unsigned pk = (unsigned)f2bf(v0) | ((unsigned)f2bf(v1) << 16);
        asm volatile("global_store_dword %0, %1, off sc0 sc1"
                     :: "v"(sout + gidx), "v"(pk) : "memory");
        __syncthreads();   // protect part[] reuse next step (no drain needed)
    }
}

// ---------------- head: logits[b,c] = sum_r s[b,r]*W_out[c,r] + bias[c] ----------------
__global__ __launch_bounds__(512) void head_kernel(const u16* __restrict__ sin,
                                                   const u16* __restrict__ wout,
                                                   const float* __restrict__ bias,
                                                   float* __restrict__ out) {
    __shared__ float part[8][32][33];
    int lane = threadIdx.x & 63;
    int w = threadIdx.x >> 6;
    int m0 = blockIdx.x * 32;
    int n0 = blockIdx.y * 32;   // over padded 1024
    int k0 = w * 256;
    int lr = lane & 15;
    int lk = (lane >> 4) * 8;

    f32x4 acc[2][2];
#pragma unroll
    for (int i = 0; i < 2; i++)
#pragma unroll
        for (int j = 0; j < 2; j++) acc[i][j] = (f32x4)0.f;

    for (int kk = k0; kk < k0 + 256; kk += 32) {
        bf16x8 a[2], b[2];
#pragma unroll
        for (int i = 0; i < 2; i++)
            a[i] = *(const bf16x8*)(sin + (size_t)(m0 + i * 16 + lr) * RES + kk + lk);
#pragma unroll
        for (int j = 0; j < 2; j++) {
            int row = n0 + j * 16 + lr;
            if (row > NCLS - 1) row = NCLS - 1;  // clamp, result unused
            b[j] = *(const bf16x8*)(wout + (size_t)row * RES + kk + lk);
        }
#pragma unroll
        for (int i = 0; i < 2; i++)
#pragma unroll
            for (int j = 0; j < 2; j++)
                acc[i][j] = __builtin_amdgcn_mfma_f32_16x16x32_bf16(a[i], b[j], acc[i][j], 0, 0, 0);
    }

    int rowbase = (lane >> 4) * 4;
#pragma unroll
    for (int i = 0; i < 2; i++)
#pragma unroll
        for (int j = 0; j < 2; j++)
#pragma unroll
            for (int q = 0; q < 4; q++)
                part[w][i * 16 + rowbase + q][j * 16 + lr] = acc[i][j][q];

    __syncthreads();

    for (int idx = threadIdx.x; idx < 1024; idx += 512) {
        int r = idx >> 5, c = idx & 31;
        float s = 0.f;
#pragma unroll
        for (int ww = 0; ww < 8; ww++) s += part[ww][r][c];
        int cg = n0 + c;
        if (cg < NCLS)
            out[(size_t)(m0 + r) * NCLS + cg] = s + bias[cg];
    }
}

extern "C" void kernel_launch(void* const* d_in, const int* in_sizes, int n_in,
                              void* d_out, int out_size, void* d_ws, size_t ws_size,
                              hipStream_t stream) {
    const float* x_f    = (const float*)d_in[0];  // [128,256,768]
    const float* res_f  = (const float*)d_in[1];  // [2048,2048]
    const float* win_f  = (const float*)d_in[2];  // [2048,768]
    const float* wout_f = (const float*)d_in[3];  // [1000,2048]
    const float* bias   = (const float*)d_in[4];  // [1000]
    float* out = (float*)d_out;

    char* ws = (char*)d_ws;
    size_t off = 0;
    auto alloc = [&](size_t bytes) -> void* {
        void* p = ws + off;
        off += (bytes + 255) & ~(size_t)255;
        return p;
    };
    u16* res_b  = (u16*)alloc((size_t)RES * RES * 2);
    u16* win_b  = (u16*)alloc((size_t)RES * EMBED * 2);
    u16* wout_b = (u16*)alloc((size_t)NCLS * RES * 2);
    u16* x_b    = (u16*)alloc((size_t)BATCH * NFRAMES * EMBED * 2);
    u16* ring   = (u16*)alloc((size_t)NFRAMES * BATCH * RES * 2);  // state ring
    u16* s0     = (u16*)alloc((size_t)BATCH * RES * 2);            // zero initial state

    // weight / input conversion to bf16
    cvt_kernel<<<dim3(1024), dim3(256), 0, stream>>>(res_f, res_b, RES * RES / 4);
    cvt_kernel<<<dim3(512), dim3(256), 0, stream>>>(win_f, win_b, RES * EMBED / 4);
    cvt_kernel<<<dim3(512), dim3(256), 0, stream>>>(wout_f, wout_b, NCLS * RES / 4);
    cvt_kernel<<<dim3(2048), dim3(256), 0, stream>>>(x_f, x_b, BATCH * NFRAMES * EMBED / 4);

    // sentinel-fill the ring (0xFFFF = -NaN bf16, unproducible by tanh);
    // zero initial state (ws poisoned 0xAA; re-init every call)
    hipMemsetAsync(ring, 0xFF, (size_t)NFRAMES * BATCH * RES * 2, stream);
    hipMemsetAsync(s0, 0, (size_t)BATCH * RES * 2, stream);

    // all 256 recurrence steps (fused proj, dataflow sync) in one launch
    void* args[] = { (void*)&res_b, (void*)&win_b, (void*)&x_b, (void*)&ring, (void*)&s0 };
    hipLaunchCooperativeKernel((const void*)recur_kernel, dim3(NWG), dim3(512),
                               args, 0, stream);

    // final state lives in ring slot 255
    const u16* sfin = ring + (size_t)(NFRAMES - 1) * BATCH * RES;
    head_kernel<<<dim3(4, 32), dim3(512), 0, stream>>>(sfin, wout_b, bias, out);
}

// Round 19
// 1126.607 us; speedup vs baseline: 1.5390x; 1.5390x over previous
//
#include <hip/hip_runtime.h>
#include <stdint.h>
#include <stddef.h>

#define BATCH 128
#define NFRAMES 256
#define EMBED 768
#define RES 2048
#define NCLS 1000
#define NWG 256

typedef __attribute__((ext_vector_type(8))) short bf16x8;
typedef __attribute__((ext_vector_type(4))) float f32x4;
typedef unsigned short u16;

__device__ inline u16 f2bf(float f) {
    union { float f; unsigned u; } v; v.f = f;
    unsigned r = v.u + 0x7FFFu + ((v.u >> 16) & 1u);
    return (u16)(r >> 16);
}
// tanh(x) = 1 - 2/(e^{2x}+1), via HW exp2 + rcp (saturates correctly)
__device__ inline float tanh_fast(float x) {
    float z = __builtin_amdgcn_exp2f(x * 2.885390081777927f);  // e^{2x}
    return 1.f - 2.f * __builtin_amdgcn_rcpf(z + 1.f);
}

// ---------------- fp32 -> bf16 convert, vectorized x4 ----------------
__global__ __launch_bounds__(256) void cvt_kernel(const float* __restrict__ in,
                                                  u16* __restrict__ out, int n4) {
    int i = blockIdx.x * blockDim.x + threadIdx.x;
    int stride = gridDim.x * blockDim.x;
    for (; i < n4; i += stride) {
        float4 v = ((const float4*)in)[i];
        ushort4 o;
        o.x = f2bf(v.x); o.y = f2bf(v.y); o.z = f2bf(v.z); o.w = f2bf(v.w);
        ((ushort4*)out)[i] = o;
    }
}

// ---------------- persistent recurrence: fused proj + streamlined sync ----------------
// 8 row-groups x 32 col-blocks = 256 WGs, tile 16 rows x 64 cols, 8 waves.
// vs R17: (1) part[] double-buffered -> post-store barrier deleted (cross-step
// reuse ordered by next step's pre-reduce barrier); (2) stamp via LDS arrival
// counter -- each wave drains its OWN stores (vmcnt is wave-scoped), lane0
// atomicAdds; the 8th arrival stamps the group flag immediately; (3) next
// step's x-projection (3 loads + 12 MFMAs) computed after stamping, off the
// critical path, seeding acc at step top.
// Ring state in u-slots (fresh addresses => cached A-loads safe, no fences).
__global__ __launch_bounds__(512, 1) void recur_kernel(const u16* __restrict__ res,
                                                       const u16* __restrict__ win,
                                                       const u16* __restrict__ xb,
                                                       u16* __restrict__ ring,
                                                       const u16* __restrict__ s0,
                                                       unsigned* __restrict__ flags) {
    __shared__ float part[2][8][16][66];
    __shared__ unsigned cnt;
    const int lane = threadIdx.x & 63;
    const int w = threadIdx.x >> 6;
    const int rowgrp = (int)(blockIdx.x & 7);
    const int colblk = (int)(blockIdx.x >> 3);
    const int m0 = rowgrp * 16;
    const int n0 = colblk * 64;
    const int lr = lane & 15;
    const int lk = (lane >> 4) * 8;
    const int rb = (lane >> 4) * 4;
    const int kbase = w * 256;       // state-GEMM K slice
    const int xkbase = w * 96;       // input-GEMM K slice (768/8)
    unsigned* myflag = flags + rowgrp * 32 + colblk;
    const unsigned* pollflag = flags + rowgrp * 32 + (lane & 31);

    if (threadIdx.x == 0) cnt = 0;

    // reservoir B-fragments (4 col-frags x 8 K-subs)
    bf16x8 bfr[4][8];
#pragma unroll
    for (int jf = 0; jf < 4; jf++)
#pragma unroll
        for (int kk = 0; kk < 8; kk++)
            bfr[jf][kk] = *(const bf16x8*)(res + (size_t)(n0 + jf * 16 + lr) * RES + kbase + kk * 32 + lk);

    // W_in B-fragments (4 col-frags x 3 K-subs of 32)
    bf16x8 wfr[4][3];
#pragma unroll
    for (int jf = 0; jf < 4; jf++)
#pragma unroll
        for (int j = 0; j < 3; j++)
            wfr[jf][j] = *(const bf16x8*)(win + (size_t)(n0 + jf * 16 + lr) * EMBED + xkbase + j * 32 + lk);

    const int er = threadIdx.x >> 5;          // 0..15
    const int ec = (threadIdx.x & 31) * 2;    // 0..62
    const size_t gidx = (size_t)(m0 + er) * RES + n0 + ec;
    const u16* xrow = xb + (size_t)(m0 + lr) * NFRAMES * EMBED + xkbase + lk;

    // prologue: x-projection for t=0
    f32x4 xacc[4];
#pragma unroll
    for (int jf = 0; jf < 4; jf++) xacc[jf] = (f32x4)0.f;
    {
        bf16x8 xa[3];
#pragma unroll
        for (int j = 0; j < 3; j++)
            asm volatile("global_load_dwordx4 %0, %1, off"
                         : "=v"(xa[j]) : "v"(xrow + j * 32));
        asm volatile("s_waitcnt vmcnt(0)" ::: "memory");
        __builtin_amdgcn_sched_barrier(0);
#pragma unroll
        for (int j = 0; j < 3; j++)
#pragma unroll
            for (int jf = 0; jf < 4; jf++)
                xacc[jf] = __builtin_amdgcn_mfma_f32_16x16x32_bf16(xa[j], wfr[jf][j], xacc[jf], 0, 0, 0);
    }

    for (int t = 0; t < NFRAMES; t++) {
        const u16* sin = (t == 0) ? s0 : ring + (size_t)(t - 1) * BATCH * RES;
        u16* sout = ring + (size_t)t * BATCH * RES;
        const u16* abase = sin + (size_t)(m0 + lr) * RES + kbase + lk;
        const int cur = t & 1;

        // wait for this row-group's producers of state[t-1]
        if (t > 0) {
            if (w == 0) {
                unsigned f;
                do {
                    asm volatile("global_load_dword %0, %1, off sc0 sc1\n\ts_waitcnt vmcnt(0)"
                                 : "=v"(f) : "v"(pollflag) : "memory");
                    if (__all((int)(f >= (unsigned)t))) break;
                    __builtin_amdgcn_s_sleep(1);
                } while (1);
            }
            __syncthreads();
        }

        // 8 A-loads (cached; ring makes it safe), pipelined state MFMAs
        bf16x8 a[8];
#pragma unroll
        for (int kk = 0; kk < 8; kk++)
            asm volatile("global_load_dwordx4 %0, %1, off"
                         : "=v"(a[kk]) : "v"(abase + kk * 32));

        f32x4 acc[4];
#pragma unroll
        for (int jf = 0; jf < 4; jf++) acc[jf] = xacc[jf];  // seed with x-projection

        asm volatile("s_waitcnt vmcnt(4)" ::: "memory");
        __builtin_amdgcn_sched_barrier(0);
#pragma unroll
        for (int kk = 0; kk < 4; kk++)
#pragma unroll
            for (int jf = 0; jf < 4; jf++)
                acc[jf] = __builtin_amdgcn_mfma_f32_16x16x32_bf16(a[kk], bfr[jf][kk], acc[jf], 0, 0, 0);
        asm volatile("s_waitcnt vmcnt(0)" ::: "memory");
        __builtin_amdgcn_sched_barrier(0);
#pragma unroll
        for (int kk = 4; kk < 8; kk++)
#pragma unroll
            for (int jf = 0; jf < 4; jf++)
                acc[jf] = __builtin_amdgcn_mfma_f32_16x16x32_bf16(a[kk], bfr[jf][kk], acc[jf], 0, 0, 0);

        // K-partials -> LDS (double-buffered)
#pragma unroll
        for (int jf = 0; jf < 4; jf++)
#pragma unroll
            for (int q = 0; q < 4; q++)
                part[cur][w][rb + q][jf * 16 + lr] = acc[jf][q];
        __syncthreads();

        // reduce 8 partials + tanh + packed write-through store
        float sx = 0.f, sy = 0.f;
#pragma unroll
        for (int ww = 0; ww < 8; ww++) {
            float2 v = *(const float2*)&part[cur][ww][er][ec];
            sx += v.x; sy += v.y;
        }
        float v0 = tanh_fast(sx);
        float v1 = tanh_fast(sy);
        unsigned pk = (unsigned)f2bf(v0) | ((unsigned)f2bf(v1) << 16);
        asm volatile("global_store_dword %0, %1, off sc0 sc1"
                     :: "v"(sout + gidx), "v"(pk) : "memory");

        // per-wave drain + arrival counter; 8th wave stamps the flag at once
        asm volatile("s_waitcnt vmcnt(0)" ::: "memory");
        if (t != NFRAMES - 1) {
            if (lane == 0) {
                unsigned old = atomicAdd(&cnt, 1u);
                if (old == (unsigned)(8 * t + 7)) {
                    unsigned stamp = (unsigned)(t + 1);
                    asm volatile("global_store_dword %0, %1, off sc0 sc1"
                                 :: "v"(myflag), "v"(stamp) : "memory");
                }
            }
            // x-projection prefetch for t+1 (off critical path; producers
            // of this group are still finishing)
            const u16* xp = xrow + (size_t)(t + 1) * EMBED;
            bf16x8 xa[3];
#pragma unroll
            for (int j = 0; j < 3; j++)
                asm volatile("global_load_dwordx4 %0, %1, off"
                             : "=v"(xa[j]) : "v"(xp + j * 32));
#pragma unroll
            for (int jf = 0; jf < 4; jf++) xacc[jf] = (f32x4)0.f;
            asm volatile("s_waitcnt vmcnt(0)" ::: "memory");
            __builtin_amdgcn_sched_barrier(0);
#pragma unroll
            for (int j = 0; j < 3; j++)
#pragma unroll
                for (int jf = 0; jf < 4; jf++)
                    xacc[jf] = __builtin_amdgcn_mfma_f32_16x16x32_bf16(xa[j], wfr[jf][j], xacc[jf], 0, 0, 0);
        }
        // no post-store barrier: part[] is double-buffered; cross-step reuse is
        // ordered by the next step's pre-reduce __syncthreads (program order).
    }
}

// ---------------- head: logits[b,c] = sum_r s[b,r]*W_out[c,r] + bias[c] ----------------
__global__ __launch_bounds__(512) void head_kernel(const u16* __restrict__ sin,
                                                   const u16* __restrict__ wout,
                                                   const float* __restrict__ bias,
                                                   float* __restrict__ out) {
    __shared__ float part[8][32][33];
    int lane = threadIdx.x & 63;
    int w = threadIdx.x >> 6;
    int m0 = blockIdx.x * 32;
    int n0 = blockIdx.y * 32;   // over padded 1024
    int k0 = w * 256;
    int lr = lane & 15;
    int lk = (lane >> 4) * 8;

    f32x4 acc[2][2];
#pragma unroll
    for (int i = 0; i < 2; i++)
#pragma unroll
        for (int j = 0; j < 2; j++) acc[i][j] = (f32x4)0.f;

    for (int kk = k0; kk < k0 + 256; kk += 32) {
        bf16x8 a[2], b[2];
#pragma unroll
        for (int i = 0; i < 2; i++)
            a[i] = *(const bf16x8*)(sin + (size_t)(m0 + i * 16 + lr) * RES + kk + lk);
#pragma unroll
        for (int j = 0; j < 2; j++) {
            int row = n0 + j * 16 + lr;
            if (row > NCLS - 1) row = NCLS - 1;  // clamp, result unused
            b[j] = *(const bf16x8*)(wout + (size_t)row * RES + kk + lk);
        }
#pragma unroll
        for (int i = 0; i < 2; i++)
#pragma unroll
            for (int j = 0; j < 2; j++)
                acc[i][j] = __builtin_amdgcn_mfma_f32_16x16x32_bf16(a[i], b[j], acc[i][j], 0, 0, 0);
    }

    int rowbase = (lane >> 4) * 4;
#pragma unroll
    for (int i = 0; i < 2; i++)
#pragma unroll
        for (int j = 0; j < 2; j++)
#pragma unroll
            for (int q = 0; q < 4; q++)
                part[w][i * 16 + rowbase + q][j * 16 + lr] = acc[i][j][q];

    __syncthreads();

    for (int idx = threadIdx.x; idx < 1024; idx += 512) {
        int r = idx >> 5, c = idx & 31;
        float s = 0.f;
#pragma unroll
        for (int ww = 0; ww < 8; ww++) s += part[ww][r][c];
        int cg = n0 + c;
        if (cg < NCLS)
            out[(size_t)(m0 + r) * NCLS + cg] = s + bias[cg];
    }
}

extern "C" void kernel_launch(void* const* d_in, const int* in_sizes, int n_in,
                              void* d_out, int out_size, void* d_ws, size_t ws_size,
                              hipStream_t stream) {
    const float* x_f    = (const float*)d_in[0];  // [128,256,768]
    const float* res_f  = (const float*)d_in[1];  // [2048,2048]
    const float* win_f  = (const float*)d_in[2];  // [2048,768]
    const float* wout_f = (const float*)d_in[3];  // [1000,2048]
    const float* bias   = (const float*)d_in[4];  // [1000]
    float* out = (float*)d_out;

    char* ws = (char*)d_ws;
    size_t off = 0;
    auto alloc = [&](size_t bytes) -> void* {
        void* p = ws + off;
        off += (bytes + 255) & ~(size_t)255;
        return p;
    };
    u16* res_b  = (u16*)alloc((size_t)RES * RES * 2);
    u16* win_b  = (u16*)alloc((size_t)RES * EMBED * 2);
    u16* wout_b = (u16*)alloc((size_t)NCLS * RES * 2);
    u16* x_b    = (u16*)alloc((size_t)BATCH * NFRAMES * EMBED * 2);
    u16* ring   = (u16*)alloc((size_t)NFRAMES * BATCH * RES * 2);  // state ring
    u16* s0     = (u16*)alloc((size_t)BATCH * RES * 2);            // zero initial state
    unsigned* flags = (unsigned*)alloc(1024);

    // weight / input conversion to bf16
    cvt_kernel<<<dim3(1024), dim3(256), 0, stream>>>(res_f, res_b, RES * RES / 4);
    cvt_kernel<<<dim3(512), dim3(256), 0, stream>>>(win_f, win_b, RES * EMBED / 4);
    cvt_kernel<<<dim3(512), dim3(256), 0, stream>>>(wout_f, wout_b, NCLS * RES / 4);
    cvt_kernel<<<dim3(2048), dim3(256), 0, stream>>>(x_f, x_b, BATCH * NFRAMES * EMBED / 4);

    // state0 = 0, flags = 0 (ws poisoned 0xAA; re-init every call)
    hipMemsetAsync(s0, 0, (size_t)BATCH * RES * 2, stream);
    hipMemsetAsync(flags, 0, 1024, stream);

    // all 256 recurrence steps (fused proj) in one cooperative launch
    void* args[] = { (void*)&res_b, (void*)&win_b, (void*)&x_b, (void*)&ring,
                     (void*)&s0, (void*)&flags };
    hipLaunchCooperativeKernel((const void*)recur_kernel, dim3(NWG), dim3(512),
                               args, 0, stream);

    // final state lives in ring slot 255
    const u16* sfin = ring + (size_t)(NFRAMES - 1) * BATCH * RES;
    head_kernel<<<dim3(4, 32), dim3(512), 0, stream>>>(sfin, wout_b, bias, out);
}